// Round 11
// baseline (1037.455 us; speedup 1.0000x reference)
//
#include <hip/hip_runtime.h>
#include <hip/hip_bf16.h>
#include <stdint.h>

#define NN 8192
#define DD 512
#define KK 31
#define HH 256
#define OO 16
#define SBATCH 4096
#define NE (NN*KK)    // 253952 directed edges
#define CTARGET 64
#define CCAP 128
#define EB 124        // edge-histogram blocks
#define EPB 2048      // edges per block (124*2048 == NE)

typedef __attribute__((ext_vector_type(8))) short bf16x8;
typedef __attribute__((ext_vector_type(4))) float f32x4;
typedef __attribute__((ext_vector_type(8))) unsigned short u16x8;

__device__ __forceinline__ float bf2f(__hip_bfloat16 v){ return __bfloat162float(v); }
__device__ __forceinline__ float bfu2f(unsigned short u){
  union { unsigned int i; float f; } w; w.i = ((unsigned int)u) << 16; return w.f;
}

__device__ __forceinline__ void async_lds16(const void* g, void* l){
  __builtin_amdgcn_global_load_lds((const __attribute__((address_space(1))) unsigned int*)g,
                                   (__attribute__((address_space(3))) unsigned int*)l, 16, 0, 0);
}

// runtime input-dtype flag: 1 = inputs are float32, 0 = inputs are bf16
__device__ __forceinline__ float ldf(const void* p, size_t i, int f){
  return f ? ((const float*)p)[i] : bf2f(((const __hip_bfloat16*)p)[i]);
}

// vectorized 4-element load with uniform dtype flag
__device__ __forceinline__ float4 ld4_dyn(const void* P, size_t off, int isf){
  if (isf) return *reinterpret_cast<const float4*>((const float*)P + off);
  ushort4 u = *reinterpret_cast<const ushort4*>((const unsigned short*)P + off);
  float4 r; r.x = bfu2f(u.x); r.y = bfu2f(u.y); r.z = bfu2f(u.z); r.w = bfu2f(u.w);
  return r;
}

// block 0: dtype-detect -> flag ; blocks 1..32: zero deg/in_count
__global__ void init_kernel(const void* feat, int* flag, double* deg, int* in_count){
  const int tid = threadIdx.x;
  if (blockIdx.x == 0){
    __shared__ int red[256];
    int cnt = 0;
    const __hip_bfloat16* fb = (const __hip_bfloat16*)feat;
    for (int m = 0; m < 16; ++m){
      float v = bf2f(fb[tid*16 + m]);
      if (!(fabsf(v) <= 100.f)) cnt++;
    }
    red[tid] = cnt; __syncthreads();
    for (int s = 128; s > 0; s >>= 1){ if (tid < s) red[tid] += red[tid+s]; __syncthreads(); }
    if (tid == 0) *flag = (red[0] > 40) ? 1 : 0;
  } else {
    int i = (blockIdx.x - 1)*256 + tid;
    if (i < NN){ deg[i] = 0.0; in_count[i] = 0; }
  }
}

// ---------------- fp32 NT GEMM, np/BLAS-exact chain ----------------
template<bool A_RAW, bool RELU, int OUTW, int BN, int THREADS>
__global__ void __launch_bounds__(THREADS)
gemm_nt_f32(const void* Ap, const void* W, const void* bias, float* C, const int* flagp){
  const int f = *flagp;
  constexpr int BSTRIDE = BN + 4;
  constexpr int TX = BN / 8;          // threads along cols (8 cols each)
  constexpr int TY = THREADS / TX;
  constexpr int TM = 128 / TY;        // rows per thread
  constexpr int ATOT = 512;           // float4s in 128x16 A tile
  constexpr int BTOT = BN * 4;        // float4s in BNx16 B tile
  constexpr int APASS = (ATOT + THREADS - 1) / THREADS;
  constexpr int BPASS = (BTOT + THREADS - 1) / THREADS;
  __shared__ float As[2][16*132];     // [k][m] transposed
  __shared__ float Bs[2][16*BSTRIDE]; // [k][n]
  const int tid = threadIdx.x;
  const int tx = tid % TX, ty = tid / TX;
  const int bm = blockIdx.y*128, bn = blockIdx.x*BN;
  float acc[TM][8] = {};
  float4 pa[APASS], pb[BPASS];

  auto load_tiles = [&](int k0){
    #pragma unroll
    for (int p = 0; p < APASS; ++p){
      int chunk = p*THREADS + tid;
      if ((ATOT % THREADS == 0) || chunk < ATOT){
        int m = chunk >> 2, c = chunk & 3;
        size_t o = (size_t)(bm+m)*DD + k0 + c*4;
        pa[p] = A_RAW ? ld4_dyn(Ap, o, f)
                      : *reinterpret_cast<const float4*>((const float*)Ap + o);
      }
    }
    #pragma unroll
    for (int p = 0; p < BPASS; ++p){
      int chunk = p*THREADS + tid;
      if ((BTOT % THREADS == 0) || chunk < BTOT){
        int m = chunk >> 2, c = chunk & 3;
        size_t o = (size_t)(bn+m)*DD + k0 + c*4;
        pb[p] = ld4_dyn(W, o, f);
      }
    }
  };
  auto store_tiles = [&](int buf){
    #pragma unroll
    for (int p = 0; p < APASS; ++p){
      int chunk = p*THREADS + tid;
      if ((ATOT % THREADS == 0) || chunk < ATOT){
        int m = chunk >> 2, c = chunk & 3;
        As[buf][(c*4+0)*132+m] = pa[p].x;
        As[buf][(c*4+1)*132+m] = pa[p].y;
        As[buf][(c*4+2)*132+m] = pa[p].z;
        As[buf][(c*4+3)*132+m] = pa[p].w;
      }
    }
    #pragma unroll
    for (int p = 0; p < BPASS; ++p){
      int chunk = p*THREADS + tid;
      if ((BTOT % THREADS == 0) || chunk < BTOT){
        int m = chunk >> 2, c = chunk & 3;
        Bs[buf][(c*4+0)*BSTRIDE+m] = pb[p].x;
        Bs[buf][(c*4+1)*BSTRIDE+m] = pb[p].y;
        Bs[buf][(c*4+2)*BSTRIDE+m] = pb[p].z;
        Bs[buf][(c*4+3)*BSTRIDE+m] = pb[p].w;
      }
    }
  };

  load_tiles(0);
  store_tiles(0);
  __syncthreads();
  for (int k0 = 16; k0 <= DD; k0 += 16){
    const int cur = ((k0 >> 4) - 1) & 1;
    const bool more = (k0 < DD);
    if (more) load_tiles(k0);          // global loads in flight during compute
    #pragma unroll
    for (int kk = 0; kk < 16; ++kk){
      float a[TM], b[8];
      *(float4*)&b[0] = *(const float4*)&Bs[cur][kk*BSTRIDE + tx*8];
      *(float4*)&b[4] = *(const float4*)&Bs[cur][kk*BSTRIDE + tx*8 + 4];
      #pragma unroll
      for (int r = 0; r < TM/4; ++r)
        *(float4*)&a[r*4] = *(const float4*)&As[cur][kk*132 + ty*TM + r*4];
      #pragma unroll
      for (int i = 0; i < TM; ++i)
        #pragma unroll
        for (int j = 0; j < 8; ++j)
          acc[i][j] = fmaf(a[i], b[j], acc[i][j]);
    }
    if (more) store_tiles(cur ^ 1);    // write next buffer (readers of it synced last iter)
    __syncthreads();
  }
  #pragma unroll
  for (int i = 0; i < TM; ++i){
    float out[8];
    #pragma unroll
    for (int j = 0; j < 8; ++j){
      int n = bn + tx*8 + j;
      float v = acc[i][j] + ldf(bias, n, f);
      if (RELU && v < 0.f) v = 0.f;
      out[j] = v;
    }
    float* cp = &C[(size_t)(bm + ty*TM + i)*OUTW + bn + tx*8];
    *(float4*)cp     = *(float4*)&out[0];
    *(float4*)(cp+4) = *(float4*)&out[4];
  }
}

// ---------------- np.linalg.norm emulation — one WAVE per row, bit-exact tree ----------------
__global__ void __launch_bounds__(256)
norm_np_kernel(float* emb, __hip_bfloat16* embbf){
  const int wave = threadIdx.x >> 6, lane = threadIdx.x & 63;
  const int row = blockIdx.x*4 + wave;
  float* h = emb + (size_t)row*DD;
  __hip_bfloat16* hb = embbf + (size_t)row*DD;
  const int b = lane >> 4, l = lane & 15;
  const float* a = h + b*128;
  float s0 = a[l]      * a[l],       s4 = a[64+l]  * a[64+l];
  float s1 = a[16+l]   * a[16+l],    s5 = a[80+l]  * a[80+l];
  float s2 = a[32+l]   * a[32+l],    s6 = a[96+l]  * a[96+l];
  float s3 = a[48+l]   * a[48+l],    s7 = a[112+l] * a[112+l];
  float t = ((s0+s4) + (s1+s5)) + ((s2+s6) + (s3+s7));
  t += __shfl_down(t, 8);
  t += __shfl_down(t, 4);
  t += __shfl_down(t, 2);
  t += __shfl_down(t, 1);          // lane 16b now holds B[b]
  float B0 = __shfl(t, 0), B1 = __shfl(t, 16), B2 = __shfl(t, 32), B3 = __shfl(t, 48);
  float total = (B0+B1) + (B2+B3);
  float nrm = fmaxf(sqrtf(total), 1e-12f);
  for (int k = lane; k < DD; k += 64){
    float v = h[k] / nrm;
    h[k] = v;
    hb[k] = __float2bfloat16(v);
  }
}

// ---------------- bf16 MFMA S-prefilter: 256x128 tile, 8 waves, BK=64, XCD swizzle ----------
__global__ void __launch_bounds__(512)
s_gemm_mfma(const unsigned short* embB, __hip_bfloat16* Sap, int row0){
  __shared__ unsigned short lds[256*64 + 128*64];   // 48 KB staging; epilogue reuses 33 KB
  unsigned short* Asm = lds;                        // [256][64]
  unsigned short* Bsm = lds + 256*64;               // [128][64]
  const int tid = threadIdx.x;
  const int wave = tid >> 6, lane = tid & 63;
  const int wm = (wave >> 1) * 64, wn = (wave & 1) * 64;
  const int bid = blockIdx.y * gridDim.x + blockIdx.x;    // x-fastest dispatch order
  const int nb  = gridDim.x * gridDim.y;                  // 1024 (divisible by 8)
  const int swz = (bid & 7) * (nb >> 3) + (bid >> 3);     // bijective XCD swizzle
  const int bn = (swz & 63) * 128;
  const int bm = (swz >> 6) * 256;
  const int lm = lane & 15, kg = lane >> 4;
  const int sr = lane >> 3;                   // 0..7 (row within 8-row transfer)
  const int sc = (lane & 7) ^ sr;             // xor-swizzled logical chunk (16B units)
  const size_t gA0 = (size_t)(row0 + bm + 32*wave + sr)*DD + sc*8;
  const size_t gB0 = (size_t)(       bn + 16*wave + sr)*DD + sc*8;
  unsigned short* lA = &Asm[(32*wave)*64];
  unsigned short* lB = &Bsm[(16*wave)*64];
  f32x4 acc[4][4] = {};
  for (int k0 = 0; k0 < DD; k0 += 64){
    #pragma unroll
    for (int t = 0; t < 4; ++t)
      async_lds16(embB + gA0 + (size_t)(t*8)*DD + k0, lA + t*8*64);
    #pragma unroll
    for (int t = 0; t < 2; ++t)
      async_lds16(embB + gB0 + (size_t)(t*8)*DD + k0, lB + t*8*64);
    __syncthreads();
    #pragma unroll
    for (int ks = 0; ks < 2; ++ks){
      bf16x8 af[4], bfr[4];
      #pragma unroll
      for (int i = 0; i < 4; ++i){
        int r = wm + i*16 + lm;
        af[i] = *(const bf16x8*)&Asm[r*64 + (((kg + 4*ks) ^ (r & 7))*8)];
      }
      #pragma unroll
      for (int j = 0; j < 4; ++j){
        int r = wn + j*16 + lm;
        bfr[j] = *(const bf16x8*)&Bsm[r*64 + (((kg + 4*ks) ^ (r & 7))*8)];
      }
      #pragma unroll
      for (int i = 0; i < 4; ++i)
        #pragma unroll
        for (int j = 0; j < 4; ++j)
          acc[i][j] = __builtin_amdgcn_mfma_f32_16x16x32_bf16(af[i], bfr[j], acc[i][j], 0, 0, 0);
    }
    __syncthreads();
  }
  // epilogue: two passes of 128 rows through LDS (stride 132), vectorized stores
  const int crow = kg * 4;
  #pragma unroll 1
  for (int p = 0; p < 2; ++p){
    if ((wave >> 2) == p){
      #pragma unroll
      for (int i = 0; i < 4; ++i)
        #pragma unroll
        for (int j = 0; j < 4; ++j)
          #pragma unroll
          for (int r = 0; r < 4; ++r){
            __hip_bfloat16 b = __float2bfloat16(acc[i][j][r]);
            lds[((wm & 127) + i*16 + crow + r)*132 + wn + j*16 + lm] = *(unsigned short*)&b;
          }
    }
    __syncthreads();
    const int rr = tid >> 2, qq = (tid & 3) * 32;
    const unsigned short* src = &lds[rr*132 + qq];
    unsigned short* dst = (unsigned short*)Sap + (size_t)(bm + p*128 + rr)*NN + bn + qq;
    #pragma unroll
    for (int q = 0; q < 4; ++q)
      *(u16x8*)(dst + q*8) = *(const u16x8*)(src + q*8);
    __syncthreads();
  }
}

// ---------------- candidate selection: binary-search threshold ----------------
__global__ void __launch_bounds__(256)
cand_kernel(const __hip_bfloat16* Sap, int row0, int* cand, int* cand_cnt){
  __shared__ int wsum[2][4];
  __shared__ int sh_cnt;
  const int rl = blockIdx.x, tid = threadIdx.x;
  const int lane = tid & 63, wave = tid >> 6;
  const unsigned short* srow = (const unsigned short*)Sap + (size_t)rl*NN;
  int iv[32];
  const u16x8* srow8 = (const u16x8*)(srow + tid*32);   // thread owns 32 contiguous elems
  #pragma unroll
  for (int q = 0; q < 4; ++q){
    u16x8 v = srow8[q];
    #pragma unroll
    for (int e = 0; e < 8; ++e){
      unsigned short u = v[e];
      iv[q*8+e] = (int)(unsigned short)(u ^ ((u & 0x8000u) ? 0xFFFFu : 0x8000u));
    }
  }
  if (tid == 0) sh_cnt = 0;
  int tau = 0;
  #pragma unroll 1
  for (int bit = 15; bit >= 0; --bit){
    const int tt = tau | (1 << bit);
    int c = 0;
    #pragma unroll
    for (int m = 0; m < 32; ++m) c += (iv[m] >= tt) ? 1 : 0;
    c += __shfl_down(c, 32);
    c += __shfl_down(c, 16);
    c += __shfl_down(c, 8);
    c += __shfl_down(c, 4);
    c += __shfl_down(c, 2);
    c += __shfl_down(c, 1);
    if (lane == 0) wsum[bit & 1][wave] = c;
    __syncthreads();
    const int* ws = wsum[bit & 1];
    if (ws[0] + ws[1] + ws[2] + ws[3] >= CTARGET) tau = tt;
  }
  #pragma unroll
  for (int m = 0; m < 32; ++m){
    if (iv[m] >= tau){
      int pos = atomicAdd(&sh_cnt, 1);
      if (pos < CCAP) cand[(size_t)(row0+rl)*CCAP + pos] = tid*32 + m;
    }
  }
  __syncthreads();
  if (tid == 0) cand_cnt[row0+rl] = (sh_cnt < CCAP) ? sh_cnt : CCAP;
}

// ---------------- exact fp32-chain rescore: wave-cooperative staging, async-split ----------
// T14: issue slice k+1's gather loads (registers) right after slice k's LDS-write barrier,
// so L2/L3 latency overlaps slice k's FMA phase. Two named register sets (svA/svB) keep all
// indexing static. Per-candidate fmaf chain unchanged -> bit-identical sval.
__global__ void __launch_bounds__(128)
rescore_kernel(const float* emb, const int* cand, const int* cand_cnt, float* sval){
  __shared__ float  ea[DD];            // 2 KB
  __shared__ int    jl[CCAP];          // 0.5 KB
  __shared__ float4 stg[CCAP][9];      // 18 KB (8 slots used, stride 9 kills bank conflicts)
  const int row = blockIdx.x, tid = threadIdx.x;
  ((float4*)ea)[tid] = ((const float4*)(emb + (size_t)row*DD))[tid];   // 128 f4 = 2 KB
  const int cnt = cand_cnt[row];
  jl[tid] = cand[(size_t)row*CCAP + tid];
  __syncthreads();
  const bool live = tid < cnt;
  const int cbase = tid >> 3;          // candidate sub-index within 16-candidate group
  const int part  = tid & 7;           // 16B chunk within candidate row slice
  float acc = 0.f;
  float4 svA[8], svB[8];

  auto issue = [&](float4 (&sv)[8], int ks){
    #pragma unroll
    for (int q = 0; q < 8; ++q){
      sv[q] = make_float4(0.f, 0.f, 0.f, 0.f);
      int c = q*16 + cbase;
      if (c < cnt)
        sv[q] = *(const float4*)(emb + (size_t)jl[c]*DD + ks*32 + part*4);
    }
  };
  auto put = [&](float4 (&sv)[8]){
    #pragma unroll
    for (int q = 0; q < 8; ++q){
      int c = q*16 + cbase;
      if (c < cnt) stg[c][part] = sv[q];
    }
  };
  auto compute = [&](int ks){
    if (live){
      const float* e = ea + ks*32;
      #pragma unroll
      for (int s = 0; s < 8; ++s){
        float4 v = stg[tid][s];
        acc = fmaf(e[s*4+0], v.x, acc);          // exact np chain, k ascending
        acc = fmaf(e[s*4+1], v.y, acc);
        acc = fmaf(e[s*4+2], v.z, acc);
        acc = fmaf(e[s*4+3], v.w, acc);
      }
    }
  };

  issue(svA, 0);
  #pragma unroll 1
  for (int ks = 0; ks < 16; ks += 2){
    put(svA);
    __syncthreads();
    if (ks + 1 < 16) issue(svB, ks + 1);   // loads fly during compute(ks)
    compute(ks);
    __syncthreads();
    put(svB);
    __syncthreads();
    if (ks + 2 < 16) issue(svA, ks + 2);   // loads fly during compute(ks+1)
    compute(ks + 1);
    __syncthreads();
  }
  if (live) sval[(size_t)row*CCAP + tid] = acc;
}

// ---------------- final top-31 + fused own-degree ----------------
__global__ void __launch_bounds__(128)
select_topk(const float* sval, const int* cand, const int* cand_cnt, float* tv, int* ti, double* deg){
  __shared__ unsigned long long keys[CCAP];
  const int row = blockIdx.x, tid = threadIdx.x;
  const int cnt = cand_cnt[row];
  unsigned long long key = 0ull;
  if (tid < cnt){
    int j = cand[(size_t)row*CCAP + tid];
    unsigned u = __float_as_uint(sval[(size_t)row*CCAP + tid]);
    u = (u & 0x80000000u) ? ~u : (u | 0x80000000u);
    key = ((unsigned long long)u << 32) | (unsigned long long)(0xFFFFFFFFu - (unsigned)j);
  }
  keys[tid] = key;
  __syncthreads();
  for (int kk = 2; kk <= CCAP; kk <<= 1){
    for (int jj = kk >> 1; jj > 0; jj >>= 1){
      int l = tid ^ jj;
      if (l > tid){
        unsigned long long a = keys[tid], b = keys[l];
        bool up = (tid & kk) == 0;             // descending
        if (up ? (a < b) : (a > b)){ keys[tid] = b; keys[l] = a; }
      }
      __syncthreads();
    }
  }
  double dv = 0.0;
  if (tid < KK){
    unsigned long long k2 = keys[tid];
    unsigned u  = (unsigned)(k2 >> 32);
    unsigned uj = 0xFFFFFFFFu - (unsigned)(k2 & 0xFFFFFFFFull);
    unsigned fv = (u & 0x80000000u) ? (u ^ 0x80000000u) : ~u;
    float v = __uint_as_float(fv);
    tv[(size_t)row*KK + tid] = v;
    ti[(size_t)row*KK + tid] = (int)uj;
    dv = (double)fmaxf(v, 0.f);
  }
  // own-side degree: wave 0 reduces the 31 kept (clamped) values; plain store
  if (tid < 64){
    dv += __shfl_down(dv, 32);
    dv += __shfl_down(dv, 16);
    dv += __shfl_down(dv, 8);
    dv += __shfl_down(dv, 4);
    dv += __shfl_down(dv, 2);
    dv += __shfl_down(dv, 1);
    if (tid == 0) deg[row] = 0.5 * dv;
  }
}

// ---------------- hub-free transpose: privatized per-block histograms ----------------
__global__ void __launch_bounds__(256)
edge_hist_kernel(const float* tv, const int* ti, int* pcnt, float* pdeg){
  __shared__ int   hc[NN];    // 32 KB
  __shared__ float hd[NN];    // 32 KB
  const int b = blockIdx.x, tid = threadIdx.x;
  for (int k = tid; k < NN; k += 256){ hc[k] = 0; hd[k] = 0.f; }
  __syncthreads();
  const int e0 = b*EPB;
  #pragma unroll
  for (int q = 0; q < EPB/256; ++q){
    int e = e0 + q*256 + tid;
    int j = ti[e];
    float s = tv[e]; if (s < 0.f) s = 0.f;
    atomicAdd(&hc[j], 1);
    atomicAdd(&hd[j], s);
  }
  __syncthreads();
  for (int k = tid; k < NN; k += 256){
    pcnt[(size_t)b*NN + k] = hc[k];
    pdeg[(size_t)b*NN + k] = hd[k];
  }
}

// k2: per-bin cross-block reduce; rewrites pcnt with per-(block,bin) exclusive prefix;
// finalizes deg[j] (own part stored by select_topk) and in_count[j]. One thread per bin.
__global__ void __launch_bounds__(256)
edge_reduce_kernel(int* pcnt, const float* pdeg, int* in_count, double* deg){
  const int j = blockIdx.x*256 + threadIdx.x;
  int csum = 0; double dsum = 0.0;
  for (int b = 0; b < EB; ++b){
    size_t o = (size_t)b*NN + j;
    int c = pcnt[o];
    pcnt[o] = csum;
    csum += c;
    dsum += (double)pdeg[o];
  }
  in_count[j] = csum;
  deg[j] += 0.5 * dsum;
}

// single block: dinv (parallel) + in_off exclusive scan
__global__ void scan_dinv_kernel(const int* in_count, int* in_off, const double* deg, double* dinv){
  __shared__ int part[256];
  const int tid = threadIdx.x;
  for (int i = tid; i < NN; i += 256) dinv[i] = 1.0 / (sqrt(deg[i]) + 1e-10);
  const int base = tid * 32;
  int local[32], sum = 0;
  for (int m = 0; m < 32; ++m){ local[m] = sum; sum += in_count[base + m]; }
  part[tid] = sum; __syncthreads();
  if (tid == 0){ int acc = 0; for (int t = 0; t < 256; ++t){ int p = part[t]; part[t] = acc; acc += p; } }
  __syncthreads();
  const int off = part[tid];
  for (int m = 0; m < 32; ++m) in_off[base + m] = off + local[m];
  if (tid == 255) in_off[NN] = NE;
}

// k3: deterministic CSR fill — rank via LDS atomics, position via in_off + block prefix.
__global__ void __launch_bounds__(256)
fill_csr_kernel(const float* tv, const int* ti, const double* dinv,
                const int* in_off, const int* pcnt, int* in_src, float* in_w, float* own_w){
  __shared__ int lrk[NN];     // 32 KB local ranks
  const int b = blockIdx.x, tid = threadIdx.x;
  for (int k = tid; k < NN; k += 256) lrk[k] = 0;
  __syncthreads();
  const int e0 = b*EPB;
  #pragma unroll
  for (int q = 0; q < EPB/256; ++q){
    int e = e0 + q*256 + tid;
    int i = e / KK;
    int j = ti[e];
    float s = tv[e]; if (s < 0.f) s = 0.f;
    float w = (float)(0.5 * (double)s * dinv[i] * dinv[j]);
    own_w[e] = w;
    int r = atomicAdd(&lrk[j], 1);
    int pos = in_off[j] + pcnt[(size_t)b*NN + j] + r;
    in_src[pos] = i;
    in_w[pos] = w;
  }
}

// ---------------- dense adj: one block per row, LDS merge, vectorized stores ----------------
__global__ void dense_fill(const int* ti, const float* own_w, const int* in_off,
                           const int* in_src, const float* in_w,
                           void* outp, const int* flagp){
  __shared__ float row[NN];
  const int f = *flagp;
  const int i = blockIdx.x, tid = threadIdx.x;
  for (int c = tid*4; c < NN; c += 1024) *(float4*)&row[c] = make_float4(0.f,0.f,0.f,0.f);
  __syncthreads();
  if (tid < KK)
    atomicAdd(&row[ti[(size_t)i*KK + tid]], own_w[(size_t)i*KK + tid]);
  const int p1 = in_off[i+1];
  for (int p = in_off[i] + tid; p < p1; p += 256)
    atomicAdd(&row[in_src[p]], in_w[p]);
  __syncthreads();
  if (f){
    float* adj = (float*)outp + (size_t)NN*OO + (size_t)i*NN;
    for (int c = tid*4; c < NN; c += 1024) *(float4*)&adj[c] = *(float4*)&row[c];
  } else {
    __hip_bfloat16* adj = (__hip_bfloat16*)outp + (size_t)NN*OO + (size_t)i*NN;
    for (int c = tid*8; c < NN; c += 2048){
      unsigned u[8];
      #pragma unroll
      for (int q = 0; q < 8; ++q){
        __hip_bfloat16 b = __float2bfloat16(row[c+q]);
        u[q] = *(unsigned short*)&b;
      }
      uint4 o;
      o.x = u[0] | (u[1]<<16); o.y = u[2] | (u[3]<<16);
      o.z = u[4] | (u[5]<<16); o.w = u[6] | (u[7]<<16);
      *(uint4*)&adj[c] = o;
    }
  }
}

// ---------------- GCN tail ----------------
__global__ void spmm1_kernel(const float* xw0, const float* own_w, const int* ti,
                             const int* in_off, const int* in_src, const float* in_w, float* x1){
  const int i = blockIdx.x, c = threadIdx.x;
  float a0 = 0.f, a1 = 0.f, a2 = 0.f, a3 = 0.f;
  const int*   oi = ti    + (size_t)i*KK;
  const float* ow = own_w + (size_t)i*KK;
  int m = 0;
  for (; m + 4 <= KK; m += 4){
    int j0 = oi[m], j1 = oi[m+1], j2 = oi[m+2], j3 = oi[m+3];
    float w0 = ow[m], w1 = ow[m+1], w2 = ow[m+2], w3 = ow[m+3];
    a0 = fmaf(w0, xw0[(size_t)j0*HH + c], a0);
    a1 = fmaf(w1, xw0[(size_t)j1*HH + c], a1);
    a2 = fmaf(w2, xw0[(size_t)j2*HH + c], a2);
    a3 = fmaf(w3, xw0[(size_t)j3*HH + c], a3);
  }
  for (; m < KK; ++m) a0 = fmaf(ow[m], xw0[(size_t)oi[m]*HH + c], a0);
  const int p0 = in_off[i], p1 = in_off[i+1];
  int p = p0;
  for (; p + 4 <= p1; p += 4){
    int j0 = in_src[p], j1 = in_src[p+1], j2 = in_src[p+2], j3 = in_src[p+3];
    float w0 = in_w[p], w1 = in_w[p+1], w2 = in_w[p+2], w3 = in_w[p+3];
    a0 = fmaf(w0, xw0[(size_t)j0*HH + c], a0);
    a1 = fmaf(w1, xw0[(size_t)j1*HH + c], a1);
    a2 = fmaf(w2, xw0[(size_t)j2*HH + c], a2);
    a3 = fmaf(w3, xw0[(size_t)j3*HH + c], a3);
  }
  for (; p < p1; ++p) a0 = fmaf(in_w[p], xw0[(size_t)in_src[p]*HH + c], a0);
  float acc = (a0 + a1) + (a2 + a3);
  x1[(size_t)i*HH + c] = acc > 0.f ? acc : 0.f;
}

__global__ void gemm_xw1(const float* x1, const void* W1, const void* b1,
                         float* xw1, const int* flagp){
  const int f = *flagp;
  __shared__ float xs[16][257];
  __shared__ float ws[16][257];
  const int tid = threadIdx.x;
  const int row0 = blockIdx.x * 16;
  for (int t = tid; t < 16*256; t += 256){
    int r = t >> 8, k = t & 255;
    xs[r][k] = x1[(size_t)(row0 + r)*HH + k];
    ws[r][k] = ldf(W1, (size_t)r*HH + k, f);
  }
  __syncthreads();
  const int r = tid >> 4, c = tid & 15;
  float a = 0.f;
  #pragma unroll 8
  for (int k = 0; k < HH; ++k) a = fmaf(xs[r][k], ws[c][k], a);
  xw1[(size_t)(row0 + r)*OO + c] = a + ldf(b1, c, f);
}

// 16 rows per 256-thread block: r = tid>>4, c = tid&15
__global__ void __launch_bounds__(256)
spmm2_kernel(const float* xw1, const float* own_w, const int* ti,
             const int* in_off, const int* in_src, const float* in_w,
             void* outp, const int* flagp){
  const int i = blockIdx.x*16 + (threadIdx.x >> 4);
  const int c = threadIdx.x & 15;
  const int f = *flagp;
  float acc = 0.f;
  const int*   oi = ti    + (size_t)i*KK;
  const float* ow = own_w + (size_t)i*KK;
  for (int m = 0; m < KK; ++m)
    acc = fmaf(ow[m], xw1[(size_t)oi[m]*OO + c], acc);
  const int p0 = in_off[i], p1 = in_off[i+1];
  for (int p = p0; p < p1; ++p)
    acc = fmaf(in_w[p], xw1[(size_t)in_src[p]*OO + c], acc);
  if (f) ((float*)outp)[(size_t)i*OO + c] = acc;
  else   ((__hip_bfloat16*)outp)[(size_t)i*OO + c] = __float2bfloat16(acc);
}

extern "C" void kernel_launch(void* const* d_in, const int* in_sizes, int n_in,
                              void* d_out, int out_size, void* d_ws, size_t ws_size,
                              hipStream_t stream) {
  (void)in_sizes; (void)n_in; (void)out_size; (void)ws_size;
  const void* features = d_in[0];
  const void* x        = d_in[1];
  const void* gsl_W0   = d_in[2];
  const void* gsl_b0   = d_in[3];
  const void* gsl_W1   = d_in[4];
  const void* gsl_b1   = d_in[5];
  const void* gcn_W0   = d_in[6];
  const void* gcn_b0   = d_in[7];
  const void* gcn_W1   = d_in[8];
  const void* gcn_b1   = d_in[9];

  // Big scratch inside the adj half of d_out (fully rewritten by dense_fill at the end).
  char* base = (char*)d_out + ((size_t)512 << 10);
  float*          h1    = (float*)(base);                               // 16MB, dead after mlp2
  float*          emb   = (float*)(base + ((size_t)16 << 20));          // 16MB, dead after rescore
  __hip_bfloat16* embbf = (__hip_bfloat16*)(base + ((size_t)32 << 20)); // 8MB
  __hip_bfloat16* Sap   = (__hip_bfloat16*)(base + ((size_t)40 << 20)); // 64MB (per 4096-row batch)
  float*          tv    = (float*)(base + ((size_t)104 << 20));         // 1MB, dead after fill
  int*            cand  = (int*)  (base + ((size_t)105 << 20));         // 4MB (8192x128)
  float*          sval  = (float*)(base + ((size_t)109 << 20));         // 4MB
  int*            ccnt  = (int*)  (base + ((size_t)113 << 20));         // 32KB
  char*           misc  =          base + ((size_t)114 << 20);          // ends ~114.2MB
  double* deg      = (double*)(misc);
  double* dinv     = (double*)(misc + 0x10000);
  int*    in_count = (int*)   (misc + 0x20000);
  // partial histograms live in the dead Sap region (k1 runs after the last cand_kernel)
  int*    pcnt = (int*)  (base + ((size_t)40 << 20));   // 3.9MB (124 x 8192)
  float*  pdeg = (float*)(base + ((size_t)45 << 20));   // 3.9MB
  float*  xw0 = (float*)(base);                       // 8MB  (reuses h1, after rescore)
  float*  x1  = (float*)(base + ((size_t)8  << 20));  // 8MB
  float*  xw1 = (float*)(base + ((size_t)16 << 20));  // 0.5MB (reuses emb, dead by then)

  // d_ws (~4.096MB): arrays surviving until dense_fill, + flag
  char* sm = (char*)d_ws;
  int*   ti     = (int*)sm;    sm += (size_t)4*NE;
  float* own_w  = (float*)sm;  sm += (size_t)4*NE;
  int*   in_src = (int*)sm;    sm += (size_t)4*NE;
  float* in_w   = (float*)sm;  sm += (size_t)4*NE;
  int*   in_off = (int*)sm;    sm += (size_t)4*(NN+1);
  int*   flagp  = (int*)sm;    sm += 4;

  init_kernel<<<dim3(33), dim3(256), 0, stream>>>(features, flagp, deg, in_count);

  // GSL MLP — emulated numpy float32 semantics (ascending-FMA chains, bit-identical order)
  gemm_nt_f32<true,  true,  DD, 128, 512><<<dim3(4,64), dim3(512), 0, stream>>>(features, gsl_W0, gsl_b0, h1,  flagp);
  gemm_nt_f32<false, false, DD, 128, 512><<<dim3(4,64), dim3(512), 0, stream>>>(h1,       gsl_W1, gsl_b1, emb, flagp);
  norm_np_kernel<<<dim3(NN/4), dim3(256), 0, stream>>>(emb, embbf);

  // bf16-MFMA prefilter + candidate selection, batched (4096 rows / batch)
  for (int b = 0; b < NN/SBATCH; ++b){
    const int row0 = b * SBATCH;
    s_gemm_mfma<<<dim3(NN/128, SBATCH/256), dim3(512), 0, stream>>>((const unsigned short*)embbf, Sap, row0);
    cand_kernel<<<dim3(SBATCH), dim3(256), 0, stream>>>(Sap, row0, cand, ccnt);
  }
  // exact rescore (async-split staged gather) + final selection (fused own-degree)
  rescore_kernel<<<dim3(NN), dim3(128), 0, stream>>>(emb, cand, ccnt, sval);
  select_topk<<<dim3(NN), dim3(128), 0, stream>>>(sval, cand, ccnt, tv, ti, deg);

  // hub-free graph assembly: privatized histograms -> reduce/prefix -> scan -> CSR fill
  edge_hist_kernel<<<dim3(EB), dim3(256), 0, stream>>>(tv, ti, pcnt, pdeg);
  edge_reduce_kernel<<<dim3(NN/256), dim3(256), 0, stream>>>(pcnt, pdeg, in_count, deg);
  scan_dinv_kernel<<<dim3(1), dim3(256), 0, stream>>>(in_count, in_off, deg, dinv);
  fill_csr_kernel<<<dim3(EB), dim3(256), 0, stream>>>(tv, ti, dinv, in_off, pcnt, in_src, in_w, own_w);

  // GCN (fp32, sparse adj) — writes outx
  gemm_nt_f32<true, false, HH, 64, 256><<<dim3(4,64), dim3(256), 0, stream>>>(x, gcn_W0, gcn_b0, xw0, flagp);
  spmm1_kernel<<<dim3(NN), dim3(256), 0, stream>>>(xw0, own_w, ti, in_off, in_src, in_w, x1);
  gemm_xw1<<<dim3(NN/16), dim3(256), 0, stream>>>(x1, gcn_W1, gcn_b1, xw1, flagp);
  spmm2_kernel<<<dim3(NN/16), dim3(256), 0, stream>>>(xw1, own_w, ti, in_off, in_src, in_w, d_out, flagp);

  // dense adj last: reads only d_ws
  dense_fill<<<dim3(NN), dim3(256), 0, stream>>>(ti, own_w, in_off, in_src, in_w, d_out, flagp);
}

// Round 12
// 1024.796 us; speedup vs baseline: 1.0124x; 1.0124x over previous
//
#include <hip/hip_runtime.h>
#include <hip/hip_bf16.h>
#include <stdint.h>

#define NN 8192
#define DD 512
#define KK 31
#define HH 256
#define OO 16
#define SBATCH 4096
#define NE (NN*KK)    // 253952 directed edges
#define CTARGET 64
#define CCAP 128
#define EB 248        // edge-histogram blocks (248*1024 == NE)
#define EPB 1024      // edges per block

typedef __attribute__((ext_vector_type(8))) short bf16x8;
typedef __attribute__((ext_vector_type(4))) float f32x4;
typedef __attribute__((ext_vector_type(8))) unsigned short u16x8;

__device__ __forceinline__ float bf2f(__hip_bfloat16 v){ return __bfloat162float(v); }
__device__ __forceinline__ float bfu2f(unsigned short u){
  union { unsigned int i; float f; } w; w.i = ((unsigned int)u) << 16; return w.f;
}

__device__ __forceinline__ void async_lds16(const void* g, void* l){
  __builtin_amdgcn_global_load_lds((const __attribute__((address_space(1))) unsigned int*)g,
                                   (__attribute__((address_space(3))) unsigned int*)l, 16, 0, 0);
}

// runtime input-dtype flag: 1 = inputs are float32, 0 = inputs are bf16
__device__ __forceinline__ float ldf(const void* p, size_t i, int f){
  return f ? ((const float*)p)[i] : bf2f(((const __hip_bfloat16*)p)[i]);
}

// vectorized 4-element load with uniform dtype flag
__device__ __forceinline__ float4 ld4_dyn(const void* P, size_t off, int isf){
  if (isf) return *reinterpret_cast<const float4*>((const float*)P + off);
  ushort4 u = *reinterpret_cast<const ushort4*>((const unsigned short*)P + off);
  float4 r; r.x = bfu2f(u.x); r.y = bfu2f(u.y); r.z = bfu2f(u.z); r.w = bfu2f(u.w);
  return r;
}

// block 0: dtype-detect -> flag ; blocks 1..32: zero deg/in_count
__global__ void init_kernel(const void* feat, int* flag, double* deg, int* in_count){
  const int tid = threadIdx.x;
  if (blockIdx.x == 0){
    __shared__ int red[256];
    int cnt = 0;
    const __hip_bfloat16* fb = (const __hip_bfloat16*)feat;
    for (int m = 0; m < 16; ++m){
      float v = bf2f(fb[tid*16 + m]);
      if (!(fabsf(v) <= 100.f)) cnt++;
    }
    red[tid] = cnt; __syncthreads();
    for (int s = 128; s > 0; s >>= 1){ if (tid < s) red[tid] += red[tid+s]; __syncthreads(); }
    if (tid == 0) *flag = (red[0] > 40) ? 1 : 0;
  } else {
    int i = (blockIdx.x - 1)*256 + tid;
    if (i < NN){ deg[i] = 0.0; in_count[i] = 0; }
  }
}

// ---------------- fp32 NT GEMM, np/BLAS-exact chain ----------------
template<bool A_RAW, bool RELU, int OUTW, int BN, int THREADS>
__global__ void __launch_bounds__(THREADS)
gemm_nt_f32(const void* Ap, const void* W, const void* bias, float* C, const int* flagp){
  const int f = *flagp;
  constexpr int BSTRIDE = BN + 4;
  constexpr int TX = BN / 8;          // threads along cols (8 cols each)
  constexpr int TY = THREADS / TX;
  constexpr int TM = 128 / TY;        // rows per thread
  constexpr int ATOT = 512;           // float4s in 128x16 A tile
  constexpr int BTOT = BN * 4;        // float4s in BNx16 B tile
  constexpr int APASS = (ATOT + THREADS - 1) / THREADS;
  constexpr int BPASS = (BTOT + THREADS - 1) / THREADS;
  __shared__ float As[2][16*132];     // [k][m] transposed
  __shared__ float Bs[2][16*BSTRIDE]; // [k][n]
  const int tid = threadIdx.x;
  const int tx = tid % TX, ty = tid / TX;
  const int bm = blockIdx.y*128, bn = blockIdx.x*BN;
  float acc[TM][8] = {};
  float4 pa[APASS], pb[BPASS];

  auto load_tiles = [&](int k0){
    #pragma unroll
    for (int p = 0; p < APASS; ++p){
      int chunk = p*THREADS + tid;
      if ((ATOT % THREADS == 0) || chunk < ATOT){
        int m = chunk >> 2, c = chunk & 3;
        size_t o = (size_t)(bm+m)*DD + k0 + c*4;
        pa[p] = A_RAW ? ld4_dyn(Ap, o, f)
                      : *reinterpret_cast<const float4*>((const float*)Ap + o);
      }
    }
    #pragma unroll
    for (int p = 0; p < BPASS; ++p){
      int chunk = p*THREADS + tid;
      if ((BTOT % THREADS == 0) || chunk < BTOT){
        int m = chunk >> 2, c = chunk & 3;
        size_t o = (size_t)(bn+m)*DD + k0 + c*4;
        pb[p] = ld4_dyn(W, o, f);
      }
    }
  };
  auto store_tiles = [&](int buf){
    #pragma unroll
    for (int p = 0; p < APASS; ++p){
      int chunk = p*THREADS + tid;
      if ((ATOT % THREADS == 0) || chunk < ATOT){
        int m = chunk >> 2, c = chunk & 3;
        As[buf][(c*4+0)*132+m] = pa[p].x;
        As[buf][(c*4+1)*132+m] = pa[p].y;
        As[buf][(c*4+2)*132+m] = pa[p].z;
        As[buf][(c*4+3)*132+m] = pa[p].w;
      }
    }
    #pragma unroll
    for (int p = 0; p < BPASS; ++p){
      int chunk = p*THREADS + tid;
      if ((BTOT % THREADS == 0) || chunk < BTOT){
        int m = chunk >> 2, c = chunk & 3;
        Bs[buf][(c*4+0)*BSTRIDE+m] = pb[p].x;
        Bs[buf][(c*4+1)*BSTRIDE+m] = pb[p].y;
        Bs[buf][(c*4+2)*BSTRIDE+m] = pb[p].z;
        Bs[buf][(c*4+3)*BSTRIDE+m] = pb[p].w;
      }
    }
  };

  load_tiles(0);
  store_tiles(0);
  __syncthreads();
  for (int k0 = 16; k0 <= DD; k0 += 16){
    const int cur = ((k0 >> 4) - 1) & 1;
    const bool more = (k0 < DD);
    if (more) load_tiles(k0);          // global loads in flight during compute
    #pragma unroll
    for (int kk = 0; kk < 16; ++kk){
      float a[TM], b[8];
      *(float4*)&b[0] = *(const float4*)&Bs[cur][kk*BSTRIDE + tx*8];
      *(float4*)&b[4] = *(const float4*)&Bs[cur][kk*BSTRIDE + tx*8 + 4];
      #pragma unroll
      for (int r = 0; r < TM/4; ++r)
        *(float4*)&a[r*4] = *(const float4*)&As[cur][kk*132 + ty*TM + r*4];
      #pragma unroll
      for (int i = 0; i < TM; ++i)
        #pragma unroll
        for (int j = 0; j < 8; ++j)
          acc[i][j] = fmaf(a[i], b[j], acc[i][j]);
    }
    if (more) store_tiles(cur ^ 1);    // write next buffer (readers of it synced last iter)
    __syncthreads();
  }
  #pragma unroll
  for (int i = 0; i < TM; ++i){
    float out[8];
    #pragma unroll
    for (int j = 0; j < 8; ++j){
      int n = bn + tx*8 + j;
      float v = acc[i][j] + ldf(bias, n, f);
      if (RELU && v < 0.f) v = 0.f;
      out[j] = v;
    }
    float* cp = &C[(size_t)(bm + ty*TM + i)*OUTW + bn + tx*8];
    *(float4*)cp     = *(float4*)&out[0];
    *(float4*)(cp+4) = *(float4*)&out[4];
  }
}

// ---------------- np.linalg.norm emulation — one WAVE per row, bit-exact tree ----------------
__global__ void __launch_bounds__(256)
norm_np_kernel(float* emb, __hip_bfloat16* embbf){
  const int wave = threadIdx.x >> 6, lane = threadIdx.x & 63;
  const int row = blockIdx.x*4 + wave;
  float* h = emb + (size_t)row*DD;
  __hip_bfloat16* hb = embbf + (size_t)row*DD;
  const int b = lane >> 4, l = lane & 15;
  const float* a = h + b*128;
  float s0 = a[l]      * a[l],       s4 = a[64+l]  * a[64+l];
  float s1 = a[16+l]   * a[16+l],    s5 = a[80+l]  * a[80+l];
  float s2 = a[32+l]   * a[32+l],    s6 = a[96+l]  * a[96+l];
  float s3 = a[48+l]   * a[48+l],    s7 = a[112+l] * a[112+l];
  float t = ((s0+s4) + (s1+s5)) + ((s2+s6) + (s3+s7));
  t += __shfl_down(t, 8);
  t += __shfl_down(t, 4);
  t += __shfl_down(t, 2);
  t += __shfl_down(t, 1);          // lane 16b now holds B[b]
  float B0 = __shfl(t, 0), B1 = __shfl(t, 16), B2 = __shfl(t, 32), B3 = __shfl(t, 48);
  float total = (B0+B1) + (B2+B3);
  float nrm = fmaxf(sqrtf(total), 1e-12f);
  for (int k = lane; k < DD; k += 64){
    float v = h[k] / nrm;
    h[k] = v;
    hb[k] = __float2bfloat16(v);
  }
}

// ---------------- bf16 MFMA S-prefilter: 256x128 tile, 8 waves, BK=64, XCD swizzle ----------
__global__ void __launch_bounds__(512)
s_gemm_mfma(const unsigned short* embB, __hip_bfloat16* Sap, int row0){
  __shared__ unsigned short lds[256*64 + 128*64];   // 48 KB staging; epilogue reuses 33 KB
  unsigned short* Asm = lds;                        // [256][64]
  unsigned short* Bsm = lds + 256*64;               // [128][64]
  const int tid = threadIdx.x;
  const int wave = tid >> 6, lane = tid & 63;
  const int wm = (wave >> 1) * 64, wn = (wave & 1) * 64;
  const int bid = blockIdx.y * gridDim.x + blockIdx.x;    // x-fastest dispatch order
  const int nb  = gridDim.x * gridDim.y;                  // 1024 (divisible by 8)
  const int swz = (bid & 7) * (nb >> 3) + (bid >> 3);     // bijective XCD swizzle
  const int bn = (swz & 63) * 128;
  const int bm = (swz >> 6) * 256;
  const int lm = lane & 15, kg = lane >> 4;
  const int sr = lane >> 3;                   // 0..7 (row within 8-row transfer)
  const int sc = (lane & 7) ^ sr;             // xor-swizzled logical chunk (16B units)
  const size_t gA0 = (size_t)(row0 + bm + 32*wave + sr)*DD + sc*8;
  const size_t gB0 = (size_t)(       bn + 16*wave + sr)*DD + sc*8;
  unsigned short* lA = &Asm[(32*wave)*64];
  unsigned short* lB = &Bsm[(16*wave)*64];
  f32x4 acc[4][4] = {};
  for (int k0 = 0; k0 < DD; k0 += 64){
    #pragma unroll
    for (int t = 0; t < 4; ++t)
      async_lds16(embB + gA0 + (size_t)(t*8)*DD + k0, lA + t*8*64);
    #pragma unroll
    for (int t = 0; t < 2; ++t)
      async_lds16(embB + gB0 + (size_t)(t*8)*DD + k0, lB + t*8*64);
    __syncthreads();
    #pragma unroll
    for (int ks = 0; ks < 2; ++ks){
      bf16x8 af[4], bfr[4];
      #pragma unroll
      for (int i = 0; i < 4; ++i){
        int r = wm + i*16 + lm;
        af[i] = *(const bf16x8*)&Asm[r*64 + (((kg + 4*ks) ^ (r & 7))*8)];
      }
      #pragma unroll
      for (int j = 0; j < 4; ++j){
        int r = wn + j*16 + lm;
        bfr[j] = *(const bf16x8*)&Bsm[r*64 + (((kg + 4*ks) ^ (r & 7))*8)];
      }
      #pragma unroll
      for (int i = 0; i < 4; ++i)
        #pragma unroll
        for (int j = 0; j < 4; ++j)
          acc[i][j] = __builtin_amdgcn_mfma_f32_16x16x32_bf16(af[i], bfr[j], acc[i][j], 0, 0, 0);
    }
    __syncthreads();
  }
  // epilogue: two passes of 128 rows through LDS (stride 132), vectorized stores
  const int crow = kg * 4;
  #pragma unroll 1
  for (int p = 0; p < 2; ++p){
    if ((wave >> 2) == p){
      #pragma unroll
      for (int i = 0; i < 4; ++i)
        #pragma unroll
        for (int j = 0; j < 4; ++j)
          #pragma unroll
          for (int r = 0; r < 4; ++r){
            __hip_bfloat16 b = __float2bfloat16(acc[i][j][r]);
            lds[((wm & 127) + i*16 + crow + r)*132 + wn + j*16 + lm] = *(unsigned short*)&b;
          }
    }
    __syncthreads();
    const int rr = tid >> 2, qq = (tid & 3) * 32;
    const unsigned short* src = &lds[rr*132 + qq];
    unsigned short* dst = (unsigned short*)Sap + (size_t)(bm + p*128 + rr)*NN + bn + qq;
    #pragma unroll
    for (int q = 0; q < 4; ++q)
      *(u16x8*)(dst + q*8) = *(const u16x8*)(src + q*8);
    __syncthreads();
  }
}

// ---------------- candidate selection: binary-search threshold ----------------
__global__ void __launch_bounds__(256)
cand_kernel(const __hip_bfloat16* Sap, int row0, int* cand, int* cand_cnt){
  __shared__ int wsum[2][4];
  __shared__ int sh_cnt;
  const int rl = blockIdx.x, tid = threadIdx.x;
  const int lane = tid & 63, wave = tid >> 6;
  const unsigned short* srow = (const unsigned short*)Sap + (size_t)rl*NN;
  int iv[32];
  const u16x8* srow8 = (const u16x8*)(srow + tid*32);   // thread owns 32 contiguous elems
  #pragma unroll
  for (int q = 0; q < 4; ++q){
    u16x8 v = srow8[q];
    #pragma unroll
    for (int e = 0; e < 8; ++e){
      unsigned short u = v[e];
      iv[q*8+e] = (int)(unsigned short)(u ^ ((u & 0x8000u) ? 0xFFFFu : 0x8000u));
    }
  }
  if (tid == 0) sh_cnt = 0;
  int tau = 0;
  #pragma unroll 1
  for (int bit = 15; bit >= 0; --bit){
    const int tt = tau | (1 << bit);
    int c = 0;
    #pragma unroll
    for (int m = 0; m < 32; ++m) c += (iv[m] >= tt) ? 1 : 0;
    c += __shfl_down(c, 32);
    c += __shfl_down(c, 16);
    c += __shfl_down(c, 8);
    c += __shfl_down(c, 4);
    c += __shfl_down(c, 2);
    c += __shfl_down(c, 1);
    if (lane == 0) wsum[bit & 1][wave] = c;
    __syncthreads();
    const int* ws = wsum[bit & 1];
    if (ws[0] + ws[1] + ws[2] + ws[3] >= CTARGET) tau = tt;
  }
  #pragma unroll
  for (int m = 0; m < 32; ++m){
    if (iv[m] >= tau){
      int pos = atomicAdd(&sh_cnt, 1);
      if (pos < CCAP) cand[(size_t)(row0+rl)*CCAP + pos] = tid*32 + m;
    }
  }
  __syncthreads();
  if (tid == 0) cand_cnt[row0+rl] = (sh_cnt < CCAP) ? sh_cnt : CCAP;
}

// ---------------- exact fp32-chain rescore: wave-cooperative LDS staging (R10 form) --------
__global__ void __launch_bounds__(128)
rescore_kernel(const float* emb, const int* cand, const int* cand_cnt, float* sval){
  __shared__ float  ea[DD];            // 2 KB
  __shared__ int    jl[CCAP];          // 0.5 KB
  __shared__ float4 stg[CCAP][9];      // 18 KB (8 slots used, stride 9 kills bank conflicts)
  const int row = blockIdx.x, tid = threadIdx.x;
  ((float4*)ea)[tid] = ((const float4*)(emb + (size_t)row*DD))[tid];   // 128 f4 = 2 KB
  const int cnt = cand_cnt[row];
  jl[tid] = cand[(size_t)row*CCAP + tid];
  __syncthreads();
  const bool live = tid < cnt;
  float acc = 0.f;
  #pragma unroll 1
  for (int ks = 0; ks < 16; ++ks){               // 16 slices x 32 floats
    float4 sv[8];
    #pragma unroll
    for (int q = 0; q < 8; ++q){
      sv[q] = make_float4(0.f, 0.f, 0.f, 0.f);
      int idx = q*128 + tid;
      int c = idx >> 3, part = idx & 7;
      if (c < cnt)
        sv[q] = *(const float4*)(emb + (size_t)jl[c]*DD + ks*32 + part*4);
    }
    #pragma unroll
    for (int q = 0; q < 8; ++q){
      int idx = q*128 + tid;
      int c = idx >> 3, part = idx & 7;
      if (c < cnt) stg[c][part] = sv[q];
    }
    __syncthreads();
    if (live){
      const float* e = ea + ks*32;
      #pragma unroll
      for (int s = 0; s < 8; ++s){
        float4 v = stg[tid][s];
        acc = fmaf(e[s*4+0], v.x, acc);          // exact np chain, k ascending
        acc = fmaf(e[s*4+1], v.y, acc);
        acc = fmaf(e[s*4+2], v.z, acc);
        acc = fmaf(e[s*4+3], v.w, acc);
      }
    }
    __syncthreads();
  }
  if (live) sval[(size_t)row*CCAP + tid] = acc;
}

// ---------------- final top-31 + fused own-degree ----------------
__global__ void __launch_bounds__(128)
select_topk(const float* sval, const int* cand, const int* cand_cnt, float* tv, int* ti, double* deg){
  __shared__ unsigned long long keys[CCAP];
  const int row = blockIdx.x, tid = threadIdx.x;
  const int cnt = cand_cnt[row];
  unsigned long long key = 0ull;
  if (tid < cnt){
    int j = cand[(size_t)row*CCAP + tid];
    unsigned u = __float_as_uint(sval[(size_t)row*CCAP + tid]);
    u = (u & 0x80000000u) ? ~u : (u | 0x80000000u);
    key = ((unsigned long long)u << 32) | (unsigned long long)(0xFFFFFFFFu - (unsigned)j);
  }
  keys[tid] = key;
  __syncthreads();
  for (int kk = 2; kk <= CCAP; kk <<= 1){
    for (int jj = kk >> 1; jj > 0; jj >>= 1){
      int l = tid ^ jj;
      if (l > tid){
        unsigned long long a = keys[tid], b = keys[l];
        bool up = (tid & kk) == 0;             // descending
        if (up ? (a < b) : (a > b)){ keys[tid] = b; keys[l] = a; }
      }
      __syncthreads();
    }
  }
  double dv = 0.0;
  if (tid < KK){
    unsigned long long k2 = keys[tid];
    unsigned u  = (unsigned)(k2 >> 32);
    unsigned uj = 0xFFFFFFFFu - (unsigned)(k2 & 0xFFFFFFFFull);
    unsigned fv = (u & 0x80000000u) ? (u ^ 0x80000000u) : ~u;
    float v = __uint_as_float(fv);
    tv[(size_t)row*KK + tid] = v;
    ti[(size_t)row*KK + tid] = (int)uj;
    dv = (double)fmaxf(v, 0.f);
  }
  // own-side degree: wave 0 reduces the 31 kept (clamped) values; plain store
  if (tid < 64){
    dv += __shfl_down(dv, 32);
    dv += __shfl_down(dv, 16);
    dv += __shfl_down(dv, 8);
    dv += __shfl_down(dv, 4);
    dv += __shfl_down(dv, 2);
    dv += __shfl_down(dv, 1);
    if (tid == 0) deg[row] = 0.5 * dv;
  }
}

// ---------------- hub-free transpose: privatized per-block histograms (EB=248) ----------
__global__ void __launch_bounds__(256)
edge_hist_kernel(const float* tv, const int* ti, int* pcnt, float* pdeg){
  __shared__ int   hc[NN];    // 32 KB
  __shared__ float hd[NN];    // 32 KB
  const int b = blockIdx.x, tid = threadIdx.x;
  for (int k = tid; k < NN; k += 256){ hc[k] = 0; hd[k] = 0.f; }
  __syncthreads();
  const int e0 = b*EPB;
  #pragma unroll
  for (int q = 0; q < EPB/256; ++q){
    int e = e0 + q*256 + tid;
    int j = ti[e];
    float s = tv[e]; if (s < 0.f) s = 0.f;
    atomicAdd(&hc[j], 1);
    atomicAdd(&hd[j], s);
  }
  __syncthreads();
  for (int k = tid; k < NN; k += 256){
    pcnt[(size_t)b*NN + k] = hc[k];
    pdeg[(size_t)b*NN + k] = hd[k];
  }
}

// k2: per-bin cross-block reduce; rewrites pcnt with per-(block,bin) exclusive prefix;
// finalizes deg[j] (own part stored by select_topk) and in_count[j]. One thread per bin.
__global__ void __launch_bounds__(256)
edge_reduce_kernel(int* pcnt, const float* pdeg, int* in_count, double* deg){
  const int j = blockIdx.x*256 + threadIdx.x;
  int csum = 0; double dsum = 0.0;
  for (int b = 0; b < EB; ++b){
    size_t o = (size_t)b*NN + j;
    int c = pcnt[o];
    pcnt[o] = csum;
    csum += c;
    dsum += (double)pdeg[o];
  }
  in_count[j] = csum;
  deg[j] += 0.5 * dsum;
}

// single block: dinv (parallel) + in_off exclusive scan
__global__ void scan_dinv_kernel(const int* in_count, int* in_off, const double* deg, double* dinv){
  __shared__ int part[256];
  const int tid = threadIdx.x;
  for (int i = tid; i < NN; i += 256) dinv[i] = 1.0 / (sqrt(deg[i]) + 1e-10);
  const int base = tid * 32;
  int local[32], sum = 0;
  for (int m = 0; m < 32; ++m){ local[m] = sum; sum += in_count[base + m]; }
  part[tid] = sum; __syncthreads();
  if (tid == 0){ int acc = 0; for (int t = 0; t < 256; ++t){ int p = part[t]; part[t] = acc; acc += p; } }
  __syncthreads();
  const int off = part[tid];
  for (int m = 0; m < 32; ++m) in_off[base + m] = off + local[m];
  if (tid == 255) in_off[NN] = NE;
}

// k3: deterministic CSR fill — rank via LDS atomics, position via in_off + block prefix.
__global__ void __launch_bounds__(256)
fill_csr_kernel(const float* tv, const int* ti, const double* dinv,
                const int* in_off, const int* pcnt, int* in_src, float* in_w, float* own_w){
  __shared__ int lrk[NN];     // 32 KB local ranks
  const int b = blockIdx.x, tid = threadIdx.x;
  for (int k = tid; k < NN; k += 256) lrk[k] = 0;
  __syncthreads();
  const int e0 = b*EPB;
  #pragma unroll
  for (int q = 0; q < EPB/256; ++q){
    int e = e0 + q*256 + tid;
    int i = e / KK;
    int j = ti[e];
    float s = tv[e]; if (s < 0.f) s = 0.f;
    float w = (float)(0.5 * (double)s * dinv[i] * dinv[j]);
    own_w[e] = w;
    int r = atomicAdd(&lrk[j], 1);
    int pos = in_off[j] + pcnt[(size_t)b*NN + j] + r;
    in_src[pos] = i;
    in_w[pos] = w;
  }
}

// ---------------- dense adj: one block per row, LDS merge, vectorized stores ----------------
__global__ void dense_fill(const int* ti, const float* own_w, const int* in_off,
                           const int* in_src, const float* in_w,
                           void* outp, const int* flagp){
  __shared__ float row[NN];
  const int f = *flagp;
  const int i = blockIdx.x, tid = threadIdx.x;
  for (int c = tid*4; c < NN; c += 1024) *(float4*)&row[c] = make_float4(0.f,0.f,0.f,0.f);
  __syncthreads();
  if (tid < KK)
    atomicAdd(&row[ti[(size_t)i*KK + tid]], own_w[(size_t)i*KK + tid]);
  const int p1 = in_off[i+1];
  for (int p = in_off[i] + tid; p < p1; p += 256)
    atomicAdd(&row[in_src[p]], in_w[p]);
  __syncthreads();
  if (f){
    float* adj = (float*)outp + (size_t)NN*OO + (size_t)i*NN;
    for (int c = tid*4; c < NN; c += 1024) *(float4*)&adj[c] = *(float4*)&row[c];
  } else {
    __hip_bfloat16* adj = (__hip_bfloat16*)outp + (size_t)NN*OO + (size_t)i*NN;
    for (int c = tid*8; c < NN; c += 2048){
      unsigned u[8];
      #pragma unroll
      for (int q = 0; q < 8; ++q){
        __hip_bfloat16 b = __float2bfloat16(row[c+q]);
        u[q] = *(unsigned short*)&b;
      }
      uint4 o;
      o.x = u[0] | (u[1]<<16); o.y = u[2] | (u[3]<<16);
      o.z = u[4] | (u[5]<<16); o.w = u[6] | (u[7]<<16);
      *(uint4*)&adj[c] = o;
    }
  }
}

// ---------------- GCN tail ----------------
__global__ void spmm1_kernel(const float* xw0, const float* own_w, const int* ti,
                             const int* in_off, const int* in_src, const float* in_w, float* x1){
  const int i = blockIdx.x, c = threadIdx.x;
  float a0 = 0.f, a1 = 0.f, a2 = 0.f, a3 = 0.f;
  const int*   oi = ti    + (size_t)i*KK;
  const float* ow = own_w + (size_t)i*KK;
  int m = 0;
  for (; m + 4 <= KK; m += 4){
    int j0 = oi[m], j1 = oi[m+1], j2 = oi[m+2], j3 = oi[m+3];
    float w0 = ow[m], w1 = ow[m+1], w2 = ow[m+2], w3 = ow[m+3];
    a0 = fmaf(w0, xw0[(size_t)j0*HH + c], a0);
    a1 = fmaf(w1, xw0[(size_t)j1*HH + c], a1);
    a2 = fmaf(w2, xw0[(size_t)j2*HH + c], a2);
    a3 = fmaf(w3, xw0[(size_t)j3*HH + c], a3);
  }
  for (; m < KK; ++m) a0 = fmaf(ow[m], xw0[(size_t)oi[m]*HH + c], a0);
  const int p0 = in_off[i], p1 = in_off[i+1];
  int p = p0;
  for (; p + 4 <= p1; p += 4){
    int j0 = in_src[p], j1 = in_src[p+1], j2 = in_src[p+2], j3 = in_src[p+3];
    float w0 = in_w[p], w1 = in_w[p+1], w2 = in_w[p+2], w3 = in_w[p+3];
    a0 = fmaf(w0, xw0[(size_t)j0*HH + c], a0);
    a1 = fmaf(w1, xw0[(size_t)j1*HH + c], a1);
    a2 = fmaf(w2, xw0[(size_t)j2*HH + c], a2);
    a3 = fmaf(w3, xw0[(size_t)j3*HH + c], a3);
  }
  for (; p < p1; ++p) a0 = fmaf(in_w[p], xw0[(size_t)in_src[p]*HH + c], a0);
  float acc = (a0 + a1) + (a2 + a3);
  x1[(size_t)i*HH + c] = acc > 0.f ? acc : 0.f;
}

__global__ void gemm_xw1(const float* x1, const void* W1, const void* b1,
                         float* xw1, const int* flagp){
  const int f = *flagp;
  __shared__ float xs[16][257];
  __shared__ float ws[16][257];
  const int tid = threadIdx.x;
  const int row0 = blockIdx.x * 16;
  for (int t = tid; t < 16*256; t += 256){
    int r = t >> 8, k = t & 255;
    xs[r][k] = x1[(size_t)(row0 + r)*HH + k];
    ws[r][k] = ldf(W1, (size_t)r*HH + k, f);
  }
  __syncthreads();
  const int r = tid >> 4, c = tid & 15;
  float a = 0.f;
  #pragma unroll 8
  for (int k = 0; k < HH; ++k) a = fmaf(xs[r][k], ws[c][k], a);
  xw1[(size_t)(row0 + r)*OO + c] = a + ldf(b1, c, f);
}

// 16 rows per 256-thread block: r = tid>>4, c = tid&15
__global__ void __launch_bounds__(256)
spmm2_kernel(const float* xw1, const float* own_w, const int* ti,
             const int* in_off, const int* in_src, const float* in_w,
             void* outp, const int* flagp){
  const int i = blockIdx.x*16 + (threadIdx.x >> 4);
  const int c = threadIdx.x & 15;
  const int f = *flagp;
  float acc = 0.f;
  const int*   oi = ti    + (size_t)i*KK;
  const float* ow = own_w + (size_t)i*KK;
  for (int m = 0; m < KK; ++m)
    acc = fmaf(ow[m], xw1[(size_t)oi[m]*OO + c], acc);
  const int p0 = in_off[i], p1 = in_off[i+1];
  for (int p = p0; p < p1; ++p)
    acc = fmaf(in_w[p], xw1[(size_t)in_src[p]*OO + c], acc);
  if (f) ((float*)outp)[(size_t)i*OO + c] = acc;
  else   ((__hip_bfloat16*)outp)[(size_t)i*OO + c] = __float2bfloat16(acc);
}

extern "C" void kernel_launch(void* const* d_in, const int* in_sizes, int n_in,
                              void* d_out, int out_size, void* d_ws, size_t ws_size,
                              hipStream_t stream) {
  (void)in_sizes; (void)n_in; (void)out_size; (void)ws_size;
  const void* features = d_in[0];
  const void* x        = d_in[1];
  const void* gsl_W0   = d_in[2];
  const void* gsl_b0   = d_in[3];
  const void* gsl_W1   = d_in[4];
  const void* gsl_b1   = d_in[5];
  const void* gcn_W0   = d_in[6];
  const void* gcn_b0   = d_in[7];
  const void* gcn_W1   = d_in[8];
  const void* gcn_b1   = d_in[9];

  // Big scratch inside the adj half of d_out (fully rewritten by dense_fill at the end).
  char* base = (char*)d_out + ((size_t)512 << 10);
  float*          h1    = (float*)(base);                               // 16MB, dead after mlp2
  float*          emb   = (float*)(base + ((size_t)16 << 20));          // 16MB, dead after rescore
  __hip_bfloat16* embbf = (__hip_bfloat16*)(base + ((size_t)32 << 20)); // 8MB
  __hip_bfloat16* Sap   = (__hip_bfloat16*)(base + ((size_t)40 << 20)); // 64MB (per 4096-row batch)
  float*          tv    = (float*)(base + ((size_t)104 << 20));         // 1MB, dead after fill
  int*            cand  = (int*)  (base + ((size_t)105 << 20));         // 4MB (8192x128)
  float*          sval  = (float*)(base + ((size_t)109 << 20));         // 4MB
  int*            ccnt  = (int*)  (base + ((size_t)113 << 20));         // 32KB
  char*           misc  =          base + ((size_t)114 << 20);          // ends ~114.2MB
  double* deg      = (double*)(misc);
  double* dinv     = (double*)(misc + 0x10000);
  int*    in_count = (int*)   (misc + 0x20000);
  // partial histograms live in the dead Sap region (k1 runs after the last cand_kernel)
  int*    pcnt = (int*)  (base + ((size_t)40 << 20));   // 7.9MB (248 x 8192)
  float*  pdeg = (float*)(base + ((size_t)50 << 20));   // 7.9MB
  float*  xw0 = (float*)(base);                       // 8MB  (reuses h1, after rescore)
  float*  x1  = (float*)(base + ((size_t)8  << 20));  // 8MB
  float*  xw1 = (float*)(base + ((size_t)16 << 20));  // 0.5MB (reuses emb, dead by then)

  // d_ws (~4.096MB): arrays surviving until dense_fill, + flag
  char* sm = (char*)d_ws;
  int*   ti     = (int*)sm;    sm += (size_t)4*NE;
  float* own_w  = (float*)sm;  sm += (size_t)4*NE;
  int*   in_src = (int*)sm;    sm += (size_t)4*NE;
  float* in_w   = (float*)sm;  sm += (size_t)4*NE;
  int*   in_off = (int*)sm;    sm += (size_t)4*(NN+1);
  int*   flagp  = (int*)sm;    sm += 4;

  init_kernel<<<dim3(33), dim3(256), 0, stream>>>(features, flagp, deg, in_count);

  // GSL MLP — emulated numpy float32 semantics (ascending-FMA chains, bit-identical order)
  gemm_nt_f32<true,  true,  DD, 128, 512><<<dim3(4,64), dim3(512), 0, stream>>>(features, gsl_W0, gsl_b0, h1,  flagp);
  gemm_nt_f32<false, false, DD, 128, 512><<<dim3(4,64), dim3(512), 0, stream>>>(h1,       gsl_W1, gsl_b1, emb, flagp);
  norm_np_kernel<<<dim3(NN/4), dim3(256), 0, stream>>>(emb, embbf);

  // bf16-MFMA prefilter + candidate selection, batched (4096 rows / batch)
  for (int b = 0; b < NN/SBATCH; ++b){
    const int row0 = b * SBATCH;
    s_gemm_mfma<<<dim3(NN/128, SBATCH/256), dim3(512), 0, stream>>>((const unsigned short*)embbf, Sap, row0);
    cand_kernel<<<dim3(SBATCH), dim3(256), 0, stream>>>(Sap, row0, cand, ccnt);
  }
  // exact rescore (wave-cooperative staged gather) + final selection (fused own-degree)
  rescore_kernel<<<dim3(NN), dim3(128), 0, stream>>>(emb, cand, ccnt, sval);
  select_topk<<<dim3(NN), dim3(128), 0, stream>>>(sval, cand, ccnt, tv, ti, deg);

  // hub-free graph assembly: privatized histograms -> reduce/prefix -> scan -> CSR fill
  edge_hist_kernel<<<dim3(EB), dim3(256), 0, stream>>>(tv, ti, pcnt, pdeg);
  edge_reduce_kernel<<<dim3(NN/256), dim3(256), 0, stream>>>(pcnt, pdeg, in_count, deg);
  scan_dinv_kernel<<<dim3(1), dim3(256), 0, stream>>>(in_count, in_off, deg, dinv);
  fill_csr_kernel<<<dim3(EB), dim3(256), 0, stream>>>(tv, ti, dinv, in_off, pcnt, in_src, in_w, own_w);

  // GCN (fp32, sparse adj) — writes outx
  gemm_nt_f32<true, false, HH, 64, 256><<<dim3(4,64), dim3(256), 0, stream>>>(x, gcn_W0, gcn_b0, xw0, flagp);
  spmm1_kernel<<<dim3(NN), dim3(256), 0, stream>>>(xw0, own_w, ti, in_off, in_src, in_w, x1);
  gemm_xw1<<<dim3(NN/16), dim3(256), 0, stream>>>(x1, gcn_W1, gcn_b1, xw1, flagp);
  spmm2_kernel<<<dim3(NN/16), dim3(256), 0, stream>>>(xw1, own_w, ti, in_off, in_src, in_w, d_out, flagp);

  // dense adj last: reads only d_ws
  dense_fill<<<dim3(NN), dim3(256), 0, stream>>>(ti, own_w, in_off, in_src, in_w, d_out, flagp);
}